// Round 5
// baseline (497.106 us; speedup 1.0000x reference)
//
#include <hip/hip_runtime.h>
#include <hip/hip_cooperative_groups.h>
#include <math.h>

namespace cg = cooperative_groups;

#define N_NODES 20000
#define N_EDGES 160000
#define EPSB 1e-5f
#define SLOPE 0.01f
#define NBLK 512
#define NTHR 256
#define GSTRIDE (NBLK * NTHR)

typedef __attribute__((ext_vector_type(8))) short short8;   // 8 bf16 (4 VGPRs)
typedef __attribute__((ext_vector_type(4))) float f32x4;    // MFMA C/D

// ---- workspace layout (float element offsets) ----
#define OFF_DEG    0        // int[20000]
#define OFF_DINV   20000    // float[20000]
#define OFF_AGG1   40000    // float[20000]
#define OFF_AGG2   60000    // float[20000]
#define OFF_CNODE  80000    // float[20000]
#define OFF_V      100000   // float[1024]
#define OFF_U      101024   // float[1024]
#define OFF_R      102048   // float[256]
#define OFF_RU     102304   // float[256]
#define OFF_S      102560   // float[256]
#define OFF_BFRAG  102816   // bf16[8 ct][8 ks][64 lane][8 j] = 32768 halves
#define OFF_RRS    119200   // float4[256] (16B aligned)

#define T_STRIDE 264   // halves; 528 B rows keep 16B alignment for ds_read_b128

__device__ __forceinline__ unsigned short f2bf(float f) {
    unsigned u = __float_as_uint(f);
    return (unsigned short)((u + 0x7FFFu + ((u >> 16) & 1u)) >> 16);   // RNE
}

// One cooperative kernel; stages separated by grid.sync().
// S0 zero -> S1 (deg atomics || v,u=W1,b1 @ W2) -> S2 prep -> S3 edges1
// -> S4 (agg2 init || r,ru,s) -> S5 (edges2 || bfrag/rrs pack) -> S6 MFMA final.
__global__ __launch_bounds__(256, 2) void KAll(
    const float* __restrict__ x, const int* __restrict__ src, const int* __restrict__ dst,
    const float* __restrict__ W1, const float* __restrict__ b1, const float* __restrict__ W2,
    const float* __restrict__ b2, const float* __restrict__ gamma, const float* __restrict__ beta,
    const float* __restrict__ mean, const float* __restrict__ var,
    const float* __restrict__ lW1, const float* __restrict__ lb1,
    const float* __restrict__ lW2, const float* __restrict__ lb2,
    int* __restrict__ deg, float* __restrict__ dinv, float* __restrict__ agg1,
    float* __restrict__ agg2, float* __restrict__ cnode,
    float* __restrict__ v, float* __restrict__ u,
    float* __restrict__ r, float* __restrict__ ru, float* __restrict__ s,
    unsigned short* __restrict__ bfrag, float4* __restrict__ rrs,
    float* __restrict__ out)
{
    cg::grid_group grid = cg::this_grid();
    __shared__ unsigned short tsh[16 * T_STRIDE];   // 8448 B
    __shared__ float a_sh[16], cn_sh[16];
    __shared__ float logits[16 * 132];              // 8448 B

    const int b   = blockIdx.x;
    const int tid = threadIdx.x;
    const int gix = b * NTHR + tid;

    // ---- S0: zero atomic-accumulation targets ----
    if (gix < N_NODES) deg[gix] = 0;
    if (gix < 1024) { v[gix] = 0.f; u[gix] = 0.f; }
    else if (gix < 1280) { int m = gix - 1024; r[m] = 0.f; ru[m] = 0.f; s[m] = 0.f; }
    grid.sync();

    // ---- S1: degree atomics (all blocks) + v/u (blocks [256,512)) ----
    for (int e = gix; e < N_EDGES; e += GSTRIDE) atomicAdd(&deg[dst[e]], 1);
    if (b >= 256) {
        int bb = b - 256;
        int k  = (bb & 3) * 256 + tid;     // 0..1023
        int c0 = (bb >> 2) * 32;           // 64 chunks of 32
        float av = 0.f, au = 0.f;
        for (int c = c0; c < c0 + 32; ++c) {
            float w = W2[c * 1024 + k];    // coalesced
            av = fmaf(W1[c], w, av);
            au = fmaf(b1[c], w, au);
        }
        atomicAdd(&v[k], av);
        atomicAdd(&u[k], au);
    }
    grid.sync();

    // ---- S2: dinv + self-loop init ----
    if (gix < N_NODES) {
        float di = rsqrtf((float)(deg[gix] + 1));   // +1 = self loop
        dinv[gix] = di;
        float d2 = di * di;
        agg1[gix]  = d2 * x[gix];
        cnode[gix] = d2;
    }
    grid.sync();

    // ---- S3: first edge aggregation ----
    for (int e = gix; e < N_EDGES; e += GSTRIDE) {
        int sn = src[e], d = dst[e];
        float nrm = dinv[sn] * dinv[d];
        atomicAdd(&agg1[d], nrm * x[sn]);
        atomicAdd(&cnode[d], nrm);
    }
    grid.sync();

    // ---- S4: agg2 self-loop init + fold BN/Linear1 into r/ru/s (blocks [480,512)) ----
    if (gix < N_NODES) agg2[gix] = dinv[gix] * dinv[gix] * agg1[gix];
    if (b >= 480) {
        int bb = b - 480, m = tid, k0 = bb * 32;
        float ar = 0.f, aru = 0.f, as = 0.f;
        for (int k = k0; k < k0 + 32; ++k) {
            float g = gamma[k] * rsqrtf(var[k] + EPSB);
            float w = lW1[k * 256 + m];
            ar  = fmaf(v[k] * g, w, ar);
            aru = fmaf(u[k] * g, w, aru);
            as  = fmaf(fmaf(b2[k] - mean[k], g, beta[k]), w, as);
        }
        if (bb == 0) as += lb1[m];
        atomicAdd(&r[m], ar);
        atomicAdd(&ru[m], aru);
        atomicAdd(&s[m], as);
    }
    grid.sync();

    // ---- S5: second edge aggregation + bfrag build (blocks [480,496)) + rrs (block 496) ----
    for (int e = gix; e < N_EDGES; e += GSTRIDE) {
        int sn = src[e], d = dst[e];
        atomicAdd(&agg2[d], dinv[sn] * dinv[d] * agg1[sn]);
    }
    if (b >= 480 && b < 496) {
        int i = (b - 480) * 256 + tid;            // 0..4095 = (ct,ks,lane)
        int ct = i >> 9, ks = (i >> 6) & 7, lane = i & 63;
        int n  = ct * 16 + (lane & 15);
        int kb = ks * 32 + (lane >> 4) * 8;
        union { unsigned short u8[8]; short8 v8; } pk;
#pragma unroll
        for (int j = 0; j < 8; ++j)
            pk.u8[j] = (n < 124) ? f2bf(lW2[(kb + j) * 124 + n]) : (unsigned short)0;
        ((short8*)bfrag)[i] = pk.v8;
    } else if (b == 496) {
        rrs[tid] = make_float4(r[tid], ru[tid], s[tid], 0.f);
    }
    grid.sync();

    // ---- S6: MFMA final stage (identical math to round-4 K6, 1250 tiles over 512 blocks) ----
    int lane = tid & 63;
    int wave = __builtin_amdgcn_readfirstlane(tid >> 6);   // 0..3
    int row  = lane & 15, quad = lane >> 4;

    short8 bf0[8], bf1[8];
#pragma unroll
    for (int ks = 0; ks < 8; ++ks) {
        bf0[ks] = ((const short8*)bfrag)[((wave * 2 + 0) * 8 + ks) * 64 + lane];
        bf1[ks] = ((const short8*)bfrag)[((wave * 2 + 1) * 8 + ks) * 64 + lane];
    }
    float4 c = rrs[tid];                        // m = tid, constant across tiles

    for (int it = 0; it < 3; ++it) {
        int tile = it * NBLK + b;               // 1250 = 2*512 + 226
        if (tile >= 1250) break;                // uniform per block
        int node0 = tile * 16;
        if (tid < 16)      a_sh[tid]       = agg2[node0 + tid];
        else if (tid < 32) cn_sh[tid - 16] = cnode[node0 + tid - 16];
        __syncthreads();                        // (0) a_sh ready; prev tsh readers done

        // Phase A: T[16 node][256 m] tile, bf16
#pragma unroll
        for (int n = 0; n < 16; ++n) {
            float t = fmaf(cn_sh[n], c.y, fmaf(a_sh[n], c.x, c.z));
            t = fmaf(SLOPE, fminf(t, 0.f), fmaxf(t, 0.f));
            tsh[n * T_STRIDE + tid] = f2bf(t);
        }
        __syncthreads();                        // (1)

        // Phase B: MFMA — wave w owns cols [32w, 32w+32)
        f32x4 acc0 = {0.f, 0.f, 0.f, 0.f}, acc1 = {0.f, 0.f, 0.f, 0.f};
        const unsigned short* tb = &tsh[row * T_STRIDE + quad * 8];
#pragma unroll
        for (int ks = 0; ks < 8; ++ks) {
            short8 af = *(const short8*)(tb + ks * 32);   // ds_read_b128
            acc0 = __builtin_amdgcn_mfma_f32_16x16x32_bf16(af, bf0[ks], acc0, 0, 0, 0);
            acc1 = __builtin_amdgcn_mfma_f32_16x16x32_bf16(af, bf1[ks], acc1, 0, 0, 0);
        }
        int colbase = wave * 32;
#pragma unroll
        for (int rg = 0; rg < 4; ++rg) {
            int rw = quad * 4 + rg;             // D: row=(lane>>4)*4+reg, col=lane&15
            logits[rw * 132 + colbase + row]      = acc0[rg];
            logits[rw * 132 + colbase + 16 + row] = acc1[rg];
        }
        __syncthreads();                        // (2)

        // log_softmax: 16 threads per node, 8 cols each (last sub: 4 valid)
        int nd = tid >> 4, sub = tid & 15, c0 = sub * 8;
        int jend = 124 - c0; if (jend > 8) jend = 8;
        float vbuf[8];
        const float* lrow = &logits[nd * 132 + c0];
        float mx = -1e30f;
        for (int j = 0; j < jend; ++j) {
            vbuf[j] = lrow[j] + lb2[c0 + j];
            mx = fmaxf(mx, vbuf[j]);
        }
        mx = fmaxf(mx, __shfl_xor(mx, 1, 16));
        mx = fmaxf(mx, __shfl_xor(mx, 2, 16));
        mx = fmaxf(mx, __shfl_xor(mx, 4, 16));
        mx = fmaxf(mx, __shfl_xor(mx, 8, 16));
        float sm = 0.f;
        for (int j = 0; j < jend; ++j) sm += __expf(vbuf[j] - mx);
        sm += __shfl_xor(sm, 1, 16);
        sm += __shfl_xor(sm, 2, 16);
        sm += __shfl_xor(sm, 4, 16);
        sm += __shfl_xor(sm, 8, 16);
        float lz = mx + __logf(sm);
        float* orow = out + (node0 + nd) * 124 + c0;
        for (int j = 0; j < jend; ++j) orow[j] = vbuf[j] - lz;
    }
}

extern "C" void kernel_launch(void* const* d_in, const int* in_sizes, int n_in,
                              void* d_out, int out_size, void* d_ws, size_t ws_size,
                              hipStream_t stream) {
    const float* x     = (const float*)d_in[0];
    const int*   ei    = (const int*)d_in[1];
    const int*   src   = ei;
    const int*   dst   = ei + N_EDGES;
    const float* W1    = (const float*)d_in[2];
    const float* b1    = (const float*)d_in[3];
    const float* W2    = (const float*)d_in[4];
    const float* b2    = (const float*)d_in[5];
    const float* gamma = (const float*)d_in[6];
    const float* beta  = (const float*)d_in[7];
    const float* rmean = (const float*)d_in[8];
    const float* rvar  = (const float*)d_in[9];
    const float* lW1   = (const float*)d_in[10];
    const float* lb1   = (const float*)d_in[11];
    const float* lW2   = (const float*)d_in[12];
    const float* lb2   = (const float*)d_in[13];
    float* out = (float*)d_out;
    float* ws  = (float*)d_ws;

    int*   deg   = (int*)(ws + OFF_DEG);
    float* dinv  = ws + OFF_DINV;
    float* agg1  = ws + OFF_AGG1;
    float* agg2  = ws + OFF_AGG2;
    float* cnode = ws + OFF_CNODE;
    float* v     = ws + OFF_V;
    float* u     = ws + OFF_U;
    float* r     = ws + OFF_R;
    float* ru    = ws + OFF_RU;
    float* s     = ws + OFF_S;
    unsigned short* bfrag = (unsigned short*)(ws + OFF_BFRAG);
    float4* rrs  = (float4*)(ws + OFF_RRS);

    void* args[] = {
        (void*)&x, (void*)&src, (void*)&dst, (void*)&W1, (void*)&b1, (void*)&W2,
        (void*)&b2, (void*)&gamma, (void*)&beta, (void*)&rmean, (void*)&rvar,
        (void*)&lW1, (void*)&lb1, (void*)&lW2, (void*)&lb2,
        (void*)&deg, (void*)&dinv, (void*)&agg1, (void*)&agg2, (void*)&cnode,
        (void*)&v, (void*)&u, (void*)&r, (void*)&ru, (void*)&s,
        (void*)&bfrag, (void*)&rrs, (void*)&out
    };
    hipLaunchCooperativeKernel((const void*)KAll, dim3(NBLK), dim3(NTHR), args, 0, stream);
}

// Round 6
// 161.319 us; speedup vs baseline: 3.0815x; 3.0815x over previous
//
#include <hip/hip_runtime.h>
#include <math.h>

#define N_NODES 20000
#define N_EDGES 160000
#define EPSB 1e-5f
#define SLOPE 0.01f

typedef __attribute__((ext_vector_type(8))) short short8;   // 8 bf16 (4 VGPRs)
typedef __attribute__((ext_vector_type(4))) float f32x4;    // MFMA C/D

// ---- workspace layout (float element offsets) ----
// zeroed region (one compact memset, 171 KB):
#define OFF_DEG    0        // int[20000]
#define OFF_AGG2   20000    // float[20000]  (edge-atomic part only; self-loop folded into KF)
#define OFF_V      40000    // float[1024]
#define OFF_U      41024    // float[1024]
#define OFF_R      42048    // float[256]
#define OFF_RU     42304    // float[256]
#define OFF_S      42560    // float[256]
#define OFF_ZEND   42816
// non-zeroed:
#define OFF_DINV   42816    // float[20000]
#define OFF_AGG1   62816    // float[20000]
#define OFF_CNODE  82816    // float[20000]
#define OFF_BFRAG  102816   // bf16[8 ct][8 ks][64 lane][8 j] = 32768 halves = 16384 floats
#define OFF_RRS    119200   // float4[256] (119200*4 % 16 == 0)

#define T_STRIDE 264   // halves; 528 B rows keep 16B alignment for ds_read_b128

__device__ __forceinline__ unsigned short f2bf(float f) {
    unsigned u = __float_as_uint(f);
    return (unsigned short)((u + 0x7FFFu + ((u >> 16) & 1u)) >> 16);   // RNE
}

// K1: blocks [0,625) degree atomics; blocks [625,881) v,u = (W1,b1) @ W2.
__global__ void K1_deg_v(const int* __restrict__ dst, int* __restrict__ deg,
                         const float* __restrict__ W1, const float* __restrict__ b1,
                         const float* __restrict__ W2,
                         float* __restrict__ v, float* __restrict__ u) {
    int b = blockIdx.x;
    if (b < 625) {
        int e = b * 256 + threadIdx.x;      // 625*256 = 160000 exact
        atomicAdd(&deg[dst[e]], 1);
    } else {
        int bb = b - 625;                   // 0..255
        int k  = (bb & 3) * 256 + threadIdx.x;
        int c0 = (bb >> 2) * 32;            // 64 chunks of 32
        float av = 0.f, au = 0.f;
        for (int c = c0; c < c0 + 32; ++c) {
            float w = W2[c * 1024 + k];     // coalesced
            av = fmaf(W1[c], w, av);
            au = fmaf(b1[c], w, au);
        }
        atomicAdd(&v[k], av);
        atomicAdd(&u[k], au);
    }
}

// K2: blocks [0,79) dinv + self-loop init of agg1/cnode; blocks [79,111) fold
// BN + Linear1 into r/ru/s (needs v,u from K1 only).
__global__ void K2_prep_rs(const int* __restrict__ deg, const float* __restrict__ x,
                           float* __restrict__ dinv, float* __restrict__ agg1,
                           float* __restrict__ cnode,
                           const float* __restrict__ v, const float* __restrict__ u,
                           const float* __restrict__ gamma, const float* __restrict__ beta,
                           const float* __restrict__ mean, const float* __restrict__ var,
                           const float* __restrict__ b2, const float* __restrict__ lW1,
                           const float* __restrict__ lb1,
                           float* __restrict__ r, float* __restrict__ ru, float* __restrict__ s) {
    int b = blockIdx.x;
    if (b < 79) {
        int i = b * 256 + threadIdx.x;
        if (i < N_NODES) {
            float di = rsqrtf((float)(deg[i] + 1));   // +1 = self loop
            dinv[i] = di;
            float d2 = di * di;
            agg1[i]  = d2 * x[i];
            cnode[i] = d2;
        }
    } else {
        int bb = b - 79, m = threadIdx.x, k0 = bb * 32;
        float ar = 0.f, aru = 0.f, as = 0.f;
        for (int k = k0; k < k0 + 32; ++k) {
            float g = gamma[k] * rsqrtf(var[k] + EPSB);
            float w = lW1[k * 256 + m];
            ar  = fmaf(v[k] * g, w, ar);
            aru = fmaf(u[k] * g, w, aru);
            as  = fmaf(fmaf(b2[k] - mean[k], g, beta[k]), w, as);
        }
        if (bb == 0) as += lb1[m];
        atomicAdd(&r[m], ar);
        atomicAdd(&ru[m], aru);
        atomicAdd(&s[m], as);
    }
}

// K3: blocks [0,625) first edge aggregation; blocks [625,641) build bf16
// B-fragments of lW2 in MFMA B-operand order (no dependencies).
__global__ void K3_edges1_bfrag(const int* __restrict__ src, const int* __restrict__ dst,
                                const float* __restrict__ dinv, const float* __restrict__ x,
                                float* __restrict__ agg1, float* __restrict__ cnode,
                                const float* __restrict__ lW2,
                                unsigned short* __restrict__ bfrag) {
    int b = blockIdx.x;
    if (b < 625) {
        int e = b * 256 + threadIdx.x;
        int sn = src[e], d = dst[e];
        float nrm = dinv[sn] * dinv[d];
        atomicAdd(&agg1[d], nrm * x[sn]);
        atomicAdd(&cnode[d], nrm);
    } else {
        int i = (b - 625) * 256 + threadIdx.x;    // 0..4095 = (ct,ks,lane)
        int ct = i >> 9, ks = (i >> 6) & 7, lane = i & 63;
        int n  = ct * 16 + (lane & 15);
        int kb = ks * 32 + (lane >> 4) * 8;
        union { unsigned short u8[8]; short8 v8; } pk;
#pragma unroll
        for (int j = 0; j < 8; ++j)
            pk.u8[j] = (n < 124) ? f2bf(lW2[(kb + j) * 124 + n]) : (unsigned short)0;
        ((short8*)bfrag)[i] = pk.v8;
    }
}

// K4: blocks [0,625) second edge aggregation (atomic part of agg2 only);
// block 625 packs rrs (needs r/ru/s from K2).
__global__ void K4_edges2_rrs(const int* __restrict__ src, const int* __restrict__ dst,
                              const float* __restrict__ dinv, const float* __restrict__ agg1,
                              float* __restrict__ agg2,
                              const float* __restrict__ r, const float* __restrict__ ru,
                              const float* __restrict__ s, float4* __restrict__ rrs) {
    int b = blockIdx.x;
    if (b < 625) {
        int e = b * 256 + threadIdx.x;
        int sn = src[e], d = dst[e];
        atomicAdd(&agg2[d], dinv[sn] * dinv[d] * agg1[sn]);
    } else {
        int i = threadIdx.x;
        rrs[i] = make_float4(r[i], ru[i], s[i], 0.f);
    }
}

// KF: MFMA final stage. Block = 256 thr (4 waves), 2 node-tiles of 16 nodes each.
// a = agg2_atomic[n] + dinv[n]^2*agg1[n]  (self-loop folded here, K4-init dispatch gone).
// Phase A: T[16 node][256 m] = leaky(a*r+cn*ru+s) as bf16 in LDS. Phase B: wave w
// owns cols [32w,32w+32): 8 ds_read_b128 A-frags x 2 preloaded B-tiles -> 16
// mfma_f32_16x16x32_bf16. Epilogue: fused log_softmax (16 thr/node) + lb2.
__global__ __launch_bounds__(256, 2) void KF_final(
    const float* __restrict__ agg2, const float* __restrict__ dinv,
    const float* __restrict__ agg1, const float* __restrict__ cnode,
    const float4* __restrict__ rrs, const short8* __restrict__ bfrag,
    const float* __restrict__ lb2, float* __restrict__ out) {
    __shared__ unsigned short tsh[16 * T_STRIDE];   // 8448 B
    __shared__ float a_sh[16], cn_sh[16];
    __shared__ float logits[16 * 132];              // 8448 B
    int tid  = threadIdx.x;
    int lane = tid & 63;
    int wave = __builtin_amdgcn_readfirstlane(tid >> 6);   // 0..3
    int row  = lane & 15, quad = lane >> 4;

    // preload B-fragments for this wave's two 16-col tiles (reused across tiles)
    short8 bf0[8], bf1[8];
#pragma unroll
    for (int ks = 0; ks < 8; ++ks) {
        bf0[ks] = bfrag[((wave * 2 + 0) * 8 + ks) * 64 + lane];
        bf1[ks] = bfrag[((wave * 2 + 1) * 8 + ks) * 64 + lane];
    }
    float4 c = rrs[tid];                            // m = tid, constant across tiles

    for (int it = 0; it < 2; ++it) {
        int node0 = (blockIdx.x * 2 + it) * 16;     // 1250 tiles = 625 blocks x 2, exact
        if (tid < 16) {
            int n = node0 + tid;
            float di = dinv[n];
            a_sh[tid] = fmaf(di * di, agg1[n], agg2[n]);   // fold self-loop
        } else if (tid < 32) {
            cn_sh[tid - 16] = cnode[node0 + tid - 16];
        }
        __syncthreads();                            // (0) a_sh ready; prev tsh readers done

        // Phase A: T tile, bf16
#pragma unroll
        for (int n = 0; n < 16; ++n) {
            float t = fmaf(cn_sh[n], c.y, fmaf(a_sh[n], c.x, c.z));
            t = fmaf(SLOPE, fminf(t, 0.f), fmaxf(t, 0.f));
            tsh[n * T_STRIDE + tid] = f2bf(t);
        }
        __syncthreads();                            // (1)

        // Phase B: MFMA — wave w owns cols [32w, 32w+32)
        f32x4 acc0 = {0.f, 0.f, 0.f, 0.f}, acc1 = {0.f, 0.f, 0.f, 0.f};
        const unsigned short* tb = &tsh[row * T_STRIDE + quad * 8];
#pragma unroll
        for (int ks = 0; ks < 8; ++ks) {
            short8 af = *(const short8*)(tb + ks * 32);   // ds_read_b128, 16B aligned
            acc0 = __builtin_amdgcn_mfma_f32_16x16x32_bf16(af, bf0[ks], acc0, 0, 0, 0);
            acc1 = __builtin_amdgcn_mfma_f32_16x16x32_bf16(af, bf1[ks], acc1, 0, 0, 0);
        }
        int colbase = wave * 32;
#pragma unroll
        for (int rg = 0; rg < 4; ++rg) {
            int rw = quad * 4 + rg;                 // D: row=(lane>>4)*4+reg, col=lane&15
            logits[rw * 132 + colbase + row]      = acc0[rg];
            logits[rw * 132 + colbase + 16 + row] = acc1[rg];
        }
        __syncthreads();                            // (2)

        // log_softmax: 16 threads per node, 8 cols each (last sub: 4 valid)
        int nd = tid >> 4, sub = tid & 15, c0 = sub * 8;
        int jend = 124 - c0; if (jend > 8) jend = 8;
        float vbuf[8];
        const float* lrow = &logits[nd * 132 + c0];
        float mx = -1e30f;
        for (int j = 0; j < jend; ++j) {
            vbuf[j] = lrow[j] + lb2[c0 + j];
            mx = fmaxf(mx, vbuf[j]);
        }
        mx = fmaxf(mx, __shfl_xor(mx, 1, 16));
        mx = fmaxf(mx, __shfl_xor(mx, 2, 16));
        mx = fmaxf(mx, __shfl_xor(mx, 4, 16));
        mx = fmaxf(mx, __shfl_xor(mx, 8, 16));
        float sm = 0.f;
        for (int j = 0; j < jend; ++j) sm += __expf(vbuf[j] - mx);
        sm += __shfl_xor(sm, 1, 16);
        sm += __shfl_xor(sm, 2, 16);
        sm += __shfl_xor(sm, 4, 16);
        sm += __shfl_xor(sm, 8, 16);
        float lz = mx + __logf(sm);
        float* orow = out + (node0 + nd) * 124 + c0;
        for (int j = 0; j < jend; ++j) orow[j] = vbuf[j] - lz;
    }
}

extern "C" void kernel_launch(void* const* d_in, const int* in_sizes, int n_in,
                              void* d_out, int out_size, void* d_ws, size_t ws_size,
                              hipStream_t stream) {
    const float* x     = (const float*)d_in[0];
    const int*   ei    = (const int*)d_in[1];
    const int*   src   = ei;
    const int*   dst   = ei + N_EDGES;
    const float* W1    = (const float*)d_in[2];
    const float* b1    = (const float*)d_in[3];
    const float* W2    = (const float*)d_in[4];
    const float* b2    = (const float*)d_in[5];
    const float* gamma = (const float*)d_in[6];
    const float* beta  = (const float*)d_in[7];
    const float* rmean = (const float*)d_in[8];
    const float* rvar  = (const float*)d_in[9];
    const float* lW1   = (const float*)d_in[10];
    const float* lb1   = (const float*)d_in[11];
    const float* lW2   = (const float*)d_in[12];
    const float* lb2   = (const float*)d_in[13];
    float* out = (float*)d_out;
    float* ws  = (float*)d_ws;

    int*   deg   = (int*)(ws + OFF_DEG);
    float* agg2  = ws + OFF_AGG2;
    float* v     = ws + OFF_V;
    float* u     = ws + OFF_U;
    float* r     = ws + OFF_R;
    float* ru    = ws + OFF_RU;
    float* s     = ws + OFF_S;
    float* dinv  = ws + OFF_DINV;
    float* agg1  = ws + OFF_AGG1;
    float* cnode = ws + OFF_CNODE;
    unsigned short* bfrag = (unsigned short*)(ws + OFF_BFRAG);
    float4* rrs  = (float4*)(ws + OFF_RRS);

    // one compact memset over all atomic-accumulation targets (171 KB)
    hipMemsetAsync(ws, 0, OFF_ZEND * sizeof(float), stream);

    K1_deg_v<<<625 + 256, 256, 0, stream>>>(dst, deg, W1, b1, W2, v, u);
    K2_prep_rs<<<79 + 32, 256, 0, stream>>>(deg, x, dinv, agg1, cnode, v, u, gamma, beta,
                                            rmean, rvar, b2, lW1, lb1, r, ru, s);
    K3_edges1_bfrag<<<625 + 16, 256, 0, stream>>>(src, dst, dinv, x, agg1, cnode, lW2, bfrag);
    K4_edges2_rrs<<<625 + 1, 256, 0, stream>>>(src, dst, dinv, agg1, agg2, r, ru, s, rrs);
    KF_final<<<625, 256, 0, stream>>>(agg2, dinv, agg1, cnode, rrs,
                                      (const short8*)bfrag, lb2, out);
}

// Round 7
// 150.898 us; speedup vs baseline: 3.2943x; 1.0691x over previous
//
#include <hip/hip_runtime.h>
#include <math.h>

#define N_NODES 20000
#define N_EDGES 160000
#define EPSB 1e-5f
#define SLOPE 0.01f

typedef __attribute__((ext_vector_type(8))) short short8;   // 8 bf16 (4 VGPRs)
typedef __attribute__((ext_vector_type(4))) float f32x4;    // MFMA C/D

// ---- workspace layout (float element offsets) ----
// zeroed region (one 331 KB memset):
#define OFF_DEG    0        // int[20000]
#define OFF_A1     20000    // float[20000] agg1 atomic part (self-loop folded into consumers)
#define OFF_CN     40000    // float[20000] cnode atomic part
#define OFF_A2     60000    // float[20000] agg2 atomic part
#define OFF_V      80000    // float[1024]
#define OFF_U      81024    // float[1024]
#define OFF_R      82048    // float[256]
#define OFF_RU     82304    // float[256]
#define OFF_S      82560    // float[256]
#define OFF_ZEND   82816
// non-zeroed:
#define OFF_BFRAG  82816    // bf16[8 ct][8 ks][64 lane][8 j] = 32768 halves = 16384 floats

#define T_STRIDE 264   // halves; 528 B rows keep 16B alignment for ds_read_b128

__device__ __forceinline__ unsigned short f2bf(float f) {
    unsigned u = __float_as_uint(f);
    return (unsigned short)((u + 0x7FFFu + ((u >> 16) & 1u)) >> 16);   // RNE
}

// E1: blocks [0,625) degree atomics; [625,881) v,u = (W1,b1)@W2; [881,897) bfrag.
__global__ void E1_deg_v_bf(const int* __restrict__ dst, int* __restrict__ deg,
                            const float* __restrict__ W1, const float* __restrict__ b1,
                            const float* __restrict__ W2, const float* __restrict__ lW2,
                            float* __restrict__ v, float* __restrict__ u,
                            unsigned short* __restrict__ bfrag) {
    int b = blockIdx.x;
    if (b < 625) {
        int e = b * 256 + threadIdx.x;      // 625*256 = 160000 exact
        atomicAdd(&deg[dst[e]], 1);
    } else if (b < 881) {
        int bb = b - 625;                   // 0..255
        int k  = (bb & 3) * 256 + threadIdx.x;
        int c0 = (bb >> 2) * 32;            // 64 chunks of 32
        float av = 0.f, au = 0.f;
        for (int c = c0; c < c0 + 32; ++c) {
            float w = W2[c * 1024 + k];     // coalesced
            av = fmaf(W1[c], w, av);
            au = fmaf(b1[c], w, au);
        }
        atomicAdd(&v[k], av);
        atomicAdd(&u[k], au);
    } else {
        int i = (b - 881) * 256 + threadIdx.x;    // 0..4095 = (ct,ks,lane)
        int ct = i >> 9, ks = (i >> 6) & 7, lane = i & 63;
        int n  = ct * 16 + (lane & 15);
        int kb = ks * 32 + (lane >> 4) * 8;
        union { unsigned short u8[8]; short8 v8; } pk;
#pragma unroll
        for (int j = 0; j < 8; ++j)
            pk.u8[j] = (n < 124) ? f2bf(lW2[(kb + j) * 124 + n]) : (unsigned short)0;
        ((short8*)bfrag)[i] = pk.v8;
    }
}

// E2: blocks [0,625) first edge aggregation (dinv computed on the fly from deg);
// blocks [625,657) fold BN + Linear1 into r/ru/s (needs v,u from E1).
__global__ void E2_edges1_rs(const int* __restrict__ src, const int* __restrict__ dst,
                             const int* __restrict__ deg, const float* __restrict__ x,
                             float* __restrict__ a1, float* __restrict__ cn,
                             const float* __restrict__ v, const float* __restrict__ u,
                             const float* __restrict__ gamma, const float* __restrict__ beta,
                             const float* __restrict__ mean, const float* __restrict__ var,
                             const float* __restrict__ b2, const float* __restrict__ lW1,
                             const float* __restrict__ lb1,
                             float* __restrict__ r, float* __restrict__ ru, float* __restrict__ s) {
    int b = blockIdx.x;
    if (b < 625) {
        int e = b * 256 + threadIdx.x;
        int sn = src[e], d = dst[e];
        float nrm = rsqrtf((float)((deg[sn] + 1) * (deg[d] + 1)));  // dinv[s]*dinv[d]
        atomicAdd(&a1[d], nrm * x[sn]);
        atomicAdd(&cn[d], nrm);
    } else {
        int bb = b - 625, m = threadIdx.x, k0 = bb * 32;
        float ar = 0.f, aru = 0.f, as = 0.f;
        for (int k = k0; k < k0 + 32; ++k) {
            float g = gamma[k] * rsqrtf(var[k] + EPSB);
            float w = lW1[k * 256 + m];
            ar  = fmaf(v[k] * g, w, ar);
            aru = fmaf(u[k] * g, w, aru);
            as  = fmaf(fmaf(b2[k] - mean[k], g, beta[k]), w, as);
        }
        if (bb == 0) as += lb1[m];
        atomicAdd(&r[m], ar);
        atomicAdd(&ru[m], aru);
        atomicAdd(&s[m], as);
    }
}

// E3: second edge aggregation; agg1_full[s] reconstructed inline
// (a1[s] + dinv[s]^2 * x[s]), dinv on the fly.
__global__ void E3_edges2(const int* __restrict__ src, const int* __restrict__ dst,
                          const int* __restrict__ deg, const float* __restrict__ x,
                          const float* __restrict__ a1, float* __restrict__ a2) {
    int e = blockIdx.x * 256 + threadIdx.x;
    int sn = src[e], d = dst[e];
    float i_s = 1.f / (float)(deg[sn] + 1);                 // dinv[s]^2
    float dd  = rsqrtf((float)(deg[d] + 1));
    float a1f = fmaf(i_s, x[sn], a1[sn]);                   // full agg1[s]
    atomicAdd(&a2[d], sqrtf(i_s) * dd * a1f);
}

// F: MFMA final stage. Block = 256 thr (4 waves), 2 node-tiles of 16 nodes.
// Self-loop terms reconstructed inline: d2=1/(deg+1); a1f=a1+d2*x;
// a=a2+d2*a1f; cnf=cn+d2. Phase A: T[16 node][256 m]=leaky(a*r+cnf*ru+s) bf16
// in LDS. Phase B: wave w owns cols [32w,32w+32): 8 ds_read_b128 A-frags x 2
// preloaded B-tiles -> 16 mfma_f32_16x16x32_bf16. Fused log_softmax + lb2.
__global__ __launch_bounds__(256, 2) void F_final(
    const int* __restrict__ deg, const float* __restrict__ x,
    const float* __restrict__ a1, const float* __restrict__ cn,
    const float* __restrict__ a2,
    const float* __restrict__ r, const float* __restrict__ ru,
    const float* __restrict__ s,
    const short8* __restrict__ bfrag, const float* __restrict__ lb2,
    float* __restrict__ out) {
    __shared__ unsigned short tsh[16 * T_STRIDE];   // 8448 B
    __shared__ float a_sh[16], cn_sh[16];
    __shared__ float logits[16 * 132];              // 8448 B
    int tid  = threadIdx.x;
    int lane = tid & 63;
    int wave = __builtin_amdgcn_readfirstlane(tid >> 6);   // 0..3
    int row  = lane & 15, quad = lane >> 4;

    // preload B-fragments for this wave's two 16-col tiles (reused across tiles)
    short8 bf0[8], bf1[8];
#pragma unroll
    for (int ks = 0; ks < 8; ++ks) {
        bf0[ks] = bfrag[((wave * 2 + 0) * 8 + ks) * 64 + lane];
        bf1[ks] = bfrag[((wave * 2 + 1) * 8 + ks) * 64 + lane];
    }
    float cr = r[tid], cu = ru[tid], cs = s[tid];   // m = tid, constant across tiles

    for (int it = 0; it < 2; ++it) {
        int node0 = (blockIdx.x * 2 + it) * 16;     // 1250 tiles = 625 blocks x 2, exact
        if (tid < 16) {
            int n = node0 + tid;
            float d2  = 1.f / (float)(deg[n] + 1);
            float a1f = fmaf(d2, x[n], a1[n]);
            a_sh[tid]  = fmaf(d2, a1f, a2[n]);
            cn_sh[tid] = cn[n] + d2;
        }
        __syncthreads();                            // (0) a_sh ready; prev tsh readers done

        // Phase A: T tile, bf16
#pragma unroll
        for (int n = 0; n < 16; ++n) {
            float t = fmaf(cn_sh[n], cu, fmaf(a_sh[n], cr, cs));
            t = fmaf(SLOPE, fminf(t, 0.f), fmaxf(t, 0.f));
            tsh[n * T_STRIDE + tid] = f2bf(t);
        }
        __syncthreads();                            // (1)

        // Phase B: MFMA — wave w owns cols [32w, 32w+32)
        f32x4 acc0 = {0.f, 0.f, 0.f, 0.f}, acc1 = {0.f, 0.f, 0.f, 0.f};
        const unsigned short* tb = &tsh[row * T_STRIDE + quad * 8];
#pragma unroll
        for (int ks = 0; ks < 8; ++ks) {
            short8 af = *(const short8*)(tb + ks * 32);   // ds_read_b128, 16B aligned
            acc0 = __builtin_amdgcn_mfma_f32_16x16x32_bf16(af, bf0[ks], acc0, 0, 0, 0);
            acc1 = __builtin_amdgcn_mfma_f32_16x16x32_bf16(af, bf1[ks], acc1, 0, 0, 0);
        }
        int colbase = wave * 32;
#pragma unroll
        for (int rg = 0; rg < 4; ++rg) {
            int rw = quad * 4 + rg;                 // D: row=(lane>>4)*4+reg, col=lane&15
            logits[rw * 132 + colbase + row]      = acc0[rg];
            logits[rw * 132 + colbase + 16 + row] = acc1[rg];
        }
        __syncthreads();                            // (2)

        // log_softmax: 16 threads per node, 8 cols each (last sub: 4 valid)
        int nd = tid >> 4, sub = tid & 15, c0 = sub * 8;
        int jend = 124 - c0; if (jend > 8) jend = 8;
        float vbuf[8];
        const float* lrow = &logits[nd * 132 + c0];
        float mx = -1e30f;
        for (int j = 0; j < jend; ++j) {
            vbuf[j] = lrow[j] + lb2[c0 + j];
            mx = fmaxf(mx, vbuf[j]);
        }
        mx = fmaxf(mx, __shfl_xor(mx, 1, 16));
        mx = fmaxf(mx, __shfl_xor(mx, 2, 16));
        mx = fmaxf(mx, __shfl_xor(mx, 4, 16));
        mx = fmaxf(mx, __shfl_xor(mx, 8, 16));
        float sm = 0.f;
        for (int j = 0; j < jend; ++j) sm += __expf(vbuf[j] - mx);
        sm += __shfl_xor(sm, 1, 16);
        sm += __shfl_xor(sm, 2, 16);
        sm += __shfl_xor(sm, 4, 16);
        sm += __shfl_xor(sm, 8, 16);
        float lz = mx + __logf(sm);
        float* orow = out + (node0 + nd) * 124 + c0;
        for (int j = 0; j < jend; ++j) orow[j] = vbuf[j] - lz;
    }
}

extern "C" void kernel_launch(void* const* d_in, const int* in_sizes, int n_in,
                              void* d_out, int out_size, void* d_ws, size_t ws_size,
                              hipStream_t stream) {
    const float* x     = (const float*)d_in[0];
    const int*   ei    = (const int*)d_in[1];
    const int*   src   = ei;
    const int*   dst   = ei + N_EDGES;
    const float* W1    = (const float*)d_in[2];
    const float* b1    = (const float*)d_in[3];
    const float* W2    = (const float*)d_in[4];
    const float* b2    = (const float*)d_in[5];
    const float* gamma = (const float*)d_in[6];
    const float* beta  = (const float*)d_in[7];
    const float* rmean = (const float*)d_in[8];
    const float* rvar  = (const float*)d_in[9];
    const float* lW1   = (const float*)d_in[10];
    const float* lb1   = (const float*)d_in[11];
    const float* lW2   = (const float*)d_in[12];
    const float* lb2   = (const float*)d_in[13];
    float* out = (float*)d_out;
    float* ws  = (float*)d_ws;

    int*   deg = (int*)(ws + OFF_DEG);
    float* a1  = ws + OFF_A1;
    float* cn  = ws + OFF_CN;
    float* a2  = ws + OFF_A2;
    float* v   = ws + OFF_V;
    float* u   = ws + OFF_U;
    float* r   = ws + OFF_R;
    float* ru  = ws + OFF_RU;
    float* s   = ws + OFF_S;
    unsigned short* bfrag = (unsigned short*)(ws + OFF_BFRAG);

    // one compact memset over all atomic-accumulation targets (331 KB)
    hipMemsetAsync(ws, 0, OFF_ZEND * sizeof(float), stream);

    E1_deg_v_bf<<<625 + 256 + 16, 256, 0, stream>>>(dst, deg, W1, b1, W2, lW2, v, u, bfrag);
    E2_edges1_rs<<<625 + 32, 256, 0, stream>>>(src, dst, deg, x, a1, cn, v, u, gamma, beta,
                                               rmean, rvar, b2, lW1, lb1, r, ru, s);
    E3_edges2<<<625, 256, 0, stream>>>(src, dst, deg, x, a1, a2);
    F_final<<<625, 256, 0, stream>>>(deg, x, a1, cn, a2, r, ru, s,
                                     (const short8*)bfrag, lb2, out);
}